// Round 9
// baseline (1987.824 us; speedup 1.0000x reference)
//
#include <hip/hip_runtime.h>
#include <math.h>

#define NB 8
#define NS 32
#define NN 2048
#define ND 64
#define NH 128
#define NE 32768
#define NT (NB*NN)
#define LN_EPS 1e-5f

typedef __attribute__((ext_vector_type(8))) short short8v;
typedef __attribute__((ext_vector_type(4))) float f32x4;
typedef __attribute__((ext_vector_type(4))) unsigned int u32x4;
typedef __attribute__((ext_vector_type(2))) unsigned int u32x2;

static __device__ inline unsigned short f2bf(float f) {
  union { float f; unsigned int u; } v; v.f = f;
  unsigned int r = v.u + 0x7fffu + ((v.u >> 16) & 1u);
  return (unsigned short)(r >> 16);
}
static __device__ inline float bf2f(unsigned short s) {
  union { unsigned int u; float f; } v; v.u = ((unsigned int)s) << 16;
  return v.f;
}

// non-temporal stores: bypass producer L2 so consumers on other XCDs
// read clean L3 lines instead of remote-dirty snoops.
static __device__ inline void nts_u32(unsigned int v, unsigned int* p) {
  __builtin_nontemporal_store(v, p);
}
static __device__ inline void nts_u32x4(u32x4 v, u32x4* p) {
  __builtin_nontemporal_store(v, p);
}
static __device__ inline void nts_us(unsigned short v, unsigned short* p) {
  __builtin_nontemporal_store(v, p);
}
static __device__ inline void nts_h(_Float16 v, _Float16* p) {
  __builtin_nontemporal_store(v, p);
}

// 16B = 8 bf16 -> 8 fp32
static __device__ inline void bf8_to_f(const unsigned short* __restrict__ p, float* f) {
  u32x4 v = *(const u32x4*)p;
#pragma unroll
  for (int i = 0; i < 4; i++) {
    union { unsigned int u; float x; } lo, hi;
    lo.u = v[i] << 16; hi.u = v[i] & 0xFFFF0000u;
    f[2*i] = lo.x; f[2*i+1] = hi.x;
  }
}
// 8B = 4 bf16 -> 4 fp32
static __device__ inline void bf4_to_f(const unsigned short* __restrict__ p, float* f) {
  u32x2 v = *(const u32x2*)p;
#pragma unroll
  for (int i = 0; i < 2; i++) {
    union { unsigned int u; float x; } lo, hi;
    lo.u = v[i] << 16; hi.u = v[i] & 0xFFFF0000u;
    f[2*i] = lo.x; f[2*i+1] = hi.x;
  }
}

// ---------------- CSR build (topology is time-invariant) ----------------

__global__ void k_count(const int* __restrict__ dst, int* __restrict__ deg) {
  int e = blockIdx.x * blockDim.x + threadIdx.x;
  if (e < NE) atomicAdd(&deg[dst[e]], 1);
}

__global__ void k_scan(const int* __restrict__ deg, int* __restrict__ row_start,
                       float* __restrict__ dinv) {
  if (threadIdx.x == 0) {
    int acc = 0;
    for (int n = 0; n < NN; n++) { row_start[n] = acc; acc += deg[n]; }
    row_start[NN] = acc;
  }
  for (int n = threadIdx.x; n < NN; n += blockDim.x) {
    dinv[n] = rsqrtf((float)(deg[n] + 1));
  }
}

__global__ void k_scatter(const int* __restrict__ src, const int* __restrict__ dst,
                          const int* __restrict__ row_start, int* __restrict__ cursor,
                          int* __restrict__ csr_src) {
  int e = blockIdx.x * blockDim.x + threadIdx.x;
  if (e < NE) {
    int d = dst[e];
    int pos = atomicAdd(&cursor[d], 1);
    csr_src[row_start[d] + pos] = src[e];
  }
}

// ---------------- weight transpose + bf16 convert (once) ----------------

__global__ void k_wcvt(const float* __restrict__ Wz, const float* __restrict__ Wr,
                       const float* __restrict__ Wc,
                       unsigned short* __restrict__ Wt_zr, unsigned short* __restrict__ Wt_c) {
  int col = blockIdx.x;   // 0..255
  int k = threadIdx.x;    // 0..191
  float v = (col < 128) ? Wz[k * 128 + col] : Wr[k * 128 + (col - 128)];
  Wt_zr[(size_t)col * 192 + k] = f2bf(v);
  if (col < 128) Wt_c[(size_t)col * 192 + k] = f2bf(Wc[k * 128 + col]);
}

// ---------------- transpose x -> xT[s][n][b][64] bf16 ----------------

__global__ __launch_bounds__(256)
void k_xT(const float* __restrict__ x, unsigned short* __restrict__ xT) {
  int blk = blockIdx.x;          // 16384 blocks: (s, group of 4 n)
  int s = blk >> 9;
  int n0 = (blk & 511) * 4;
  int t = threadIdx.x;
  int b = t >> 5;
  int d2 = (t & 31) * 2;
#pragma unroll
  for (int i = 0; i < 4; i++) {
    int n = n0 + i;
    const float2 v = *(const float2*)(x + (((size_t)b * NS + s) * NN + n) * ND + d2);
    unsigned int p = ((unsigned int)f2bf(v.y) << 16) | f2bf(v.x);
    nts_u32(p, (unsigned int*)(xT + (((size_t)s * NN + n) * NB + b) * ND + d2));
  }
}

// ---------------- Xa[s][n][b][64] = A_hat @ x (all steps) -----------------

__global__ __launch_bounds__(256)
void k_aggX2(const unsigned short* __restrict__ xT, const int* __restrict__ row_start,
             const int* __restrict__ csr_src, const float* __restrict__ dinv,
             unsigned short* __restrict__ Xa) {
  int bid = blockIdx.x;                     // 16384
  int bs = (bid & 7) * 2048 + (bid >> 3);   // XCD chunking: 4 s-slabs per XCD
  int rid = bs * 4 + (threadIdx.x >> 6);    // (s,n) id, 0..65535
  int lane = threadIdx.x & 63;
  int s = rid >> 11, n = rid & 2047;
  const unsigned short* xs = xT + (size_t)s * (NN * NB * ND);
  float dn = dinv[n];
  float acc[8], val[8];
  bf8_to_f(xs + (size_t)n * 512 + lane * 8, val);
#pragma unroll
  for (int i = 0; i < 8; i++) acc[i] = dn * val[i];
  int k0 = row_start[n], k1 = row_start[n + 1];
  for (int kb = k0; kb < k1; kb += 64) {
    int m = k1 - kb; if (m > 64) m = 64;
    int idx = 0; float wv = 0.f;
    if (lane < m) { idx = csr_src[kb + lane]; wv = dinv[idx]; }
#pragma unroll 4
    for (int k = 0; k < m; k++) {
      int sn = __shfl(idx, k, 64);
      float ww = __shfl(wv, k, 64);
      bf8_to_f(xs + (size_t)sn * 512 + lane * 8, val);
#pragma unroll
      for (int i = 0; i < 8; i++) acc[i] = fmaf(ww, val[i], acc[i]);
    }
  }
  unsigned int pk[4];
#pragma unroll
  for (int i = 0; i < 4; i++)
    pk[i] = ((unsigned int)f2bf(dn * acc[2*i+1]) << 16) | f2bf(dn * acc[2*i]);
  nts_u32x4(*(u32x4*)pk, (u32x4*)(Xa + (size_t)rid * 512 + lane * 8));
}

// ---------------- phase A: agg(hB) + [Xa|ha]@[Wz|Wr] + gates ----------------
// 512 thr = 8 waves, 2 nodes/block. Gather: wave w -> node j=w>>2, quarter q=w&3.
// GEMM rows 16 (r: n=n0+(r>>3), b=r&7); wave w -> col-tiles 2w,2w+1 of [Wz|Wr].

__global__ __launch_bounds__(512, 4)
void k_zrF(const unsigned short* __restrict__ Xa, const unsigned short* __restrict__ hB,
           const unsigned short* __restrict__ Wt,
           const int* __restrict__ row_start, const int* __restrict__ csr_src,
           const float* __restrict__ dinv,
           const float* __restrict__ bz, const float* __restrict__ br,
           _Float16* __restrict__ zH, unsigned short* __restrict__ rhB, int s) {
  __shared__ unsigned short ha[16 * 128];
  int tid = threadIdx.x;
  int lane = tid & 63;
  int w = tid >> 6;
  int n0 = blockIdx.x * 2;
  int j = w >> 2, q = w & 3;
  int n = n0 + j;
  float dn = dinv[n];
  float acc[4], val[4];
  int foff = q * 256 + lane * 4;            // element in [0,1024) of node row
  bf4_to_f(hB + (size_t)n * (NB * NH) + foff, val);
#pragma unroll
  for (int i = 0; i < 4; i++) acc[i] = dn * val[i];
  int k0 = row_start[n], k1 = row_start[n + 1];
  for (int kb = k0; kb < k1; kb += 64) {
    int m = k1 - kb; if (m > 64) m = 64;
    int idx = 0; float wv = 0.f;
    if (lane < m) { idx = csr_src[kb + lane]; wv = dinv[idx]; }
#pragma unroll 4
    for (int k = 0; k < m; k++) {
      int sn = __shfl(idx, k, 64);
      float ww = __shfl(wv, k, 64);
      bf4_to_f(hB + (size_t)sn * (NB * NH) + foff, val);
#pragma unroll
      for (int i = 0; i < 4; i++) acc[i] = fmaf(ww, val[i], acc[i]);
    }
  }
  {  // LDS [16][128] bf16, XOR-swizzled; row = j*8 + b
    int row = j * 8 + (foff >> 7);
    int fe = foff & 127;
    unsigned int pk[2];
#pragma unroll
    for (int i = 0; i < 2; i++)
      pk[i] = ((unsigned int)f2bf(dn * acc[2*i+1]) << 16) | f2bf(dn * acc[2*i]);
    int byte = (row * 256 + fe * 2) ^ ((row & 7) << 4);
    *(u32x2*)((char*)ha + byte) = *(u32x2*)pk;
  }
  __syncthreads();
  // ---- GEMM
  int ar = lane & 15;
  int koff = (lane >> 4) * 8;
  short8v afr[6];
  const unsigned short* xrow =
      Xa + (((size_t)s * NN + n0 + (ar >> 3)) * NB + (ar & 7)) * ND;
  afr[0] = *(const short8v*)(xrow + koff);
  afr[1] = *(const short8v*)(xrow + 32 + koff);
#pragma unroll
  for (int kb = 2; kb < 6; kb++) {
    int kk = (kb - 2) * 32 + koff;
    int byte = (ar * 256 + kk * 2) ^ ((ar & 7) << 4);
    afr[kb] = *(const short8v*)((char*)ha + byte);
  }
  f32x4 cacc[2];
  cacc[0] = (f32x4){0.f, 0.f, 0.f, 0.f};
  cacc[1] = (f32x4){0.f, 0.f, 0.f, 0.f};
#pragma unroll
  for (int ct = 0; ct < 2; ct++) {
    const unsigned short* wcol = Wt + (size_t)((2 * w + ct) * 16 + (lane & 15)) * 192;
#pragma unroll
    for (int kb = 0; kb < 6; kb++) {
      short8v bfr = *(const short8v*)(wcol + kb * 32 + koff);
      cacc[ct] = __builtin_amdgcn_mfma_f32_16x16x32_bf16(afr[kb], bfr, cacc[ct], 0, 0, 0);
    }
  }
  // ---- epilogue: waves 0-3 -> z (fp16); waves 4-7 -> rhB = sigmoid(r)*h
  int r0 = (lane >> 4) * 4;
#pragma unroll
  for (int ct = 0; ct < 2; ct++) {
    int col = (2 * w + ct) * 16 + (lane & 15);
    int isz = (col < 128);
    int f = isz ? col : col - 128;
    float bias = isz ? bz[f] : br[f];
#pragma unroll
    for (int qq = 0; qq < 4; qq++) {
      int r = r0 + qq;
      size_t gidx = (((size_t)(n0 + (r >> 3))) * NB + (r & 7)) * NH + f;
      float g = cacc[ct][qq] + bias;
      float sg = 1.f / (1.f + __expf(-g));
      if (isz) nts_h((_Float16)sg, zH + gidx);
      else nts_us(f2bf(sg * bf2f(hB[gidx])), rhB + gidx);
    }
  }
}

// ---------------- phase B: agg(rhB) + @Wc + tanh + gate + LN ----------------
// 512 thr; wave w -> col-tile w (of 8). LN across 8 waves via LDS.

__global__ __launch_bounds__(512, 4)
void k_cF(const unsigned short* __restrict__ Xa, const unsigned short* __restrict__ rhB,
          const _Float16* __restrict__ zH, const unsigned short* __restrict__ Wt,
          const int* __restrict__ row_start, const int* __restrict__ csr_src,
          const float* __restrict__ dinv, const float* __restrict__ bc,
          const float* __restrict__ gamma, const float* __restrict__ beta,
          unsigned short* __restrict__ hB, int s) {
  __shared__ unsigned short rha[16 * 128];
  __shared__ float lsum[8][16], lsq[8][16];
  int tid = threadIdx.x;
  int lane = tid & 63;
  int w = tid >> 6;
  int n0 = blockIdx.x * 2;
  int j = w >> 2, q = w & 3;
  int n = n0 + j;
  float dn = dinv[n];
  float acc[4], val[4];
  int foff = q * 256 + lane * 4;
  bf4_to_f(rhB + (size_t)n * (NB * NH) + foff, val);
#pragma unroll
  for (int i = 0; i < 4; i++) acc[i] = dn * val[i];
  int k0 = row_start[n], k1 = row_start[n + 1];
  for (int kb = k0; kb < k1; kb += 64) {
    int m = k1 - kb; if (m > 64) m = 64;
    int idx = 0; float wv = 0.f;
    if (lane < m) { idx = csr_src[kb + lane]; wv = dinv[idx]; }
#pragma unroll 4
    for (int k = 0; k < m; k++) {
      int sn = __shfl(idx, k, 64);
      float ww = __shfl(wv, k, 64);
      bf4_to_f(rhB + (size_t)sn * (NB * NH) + foff, val);
#pragma unroll
      for (int i = 0; i < 4; i++) acc[i] = fmaf(ww, val[i], acc[i]);
    }
  }
  {
    int row = j * 8 + (foff >> 7);
    int fe = foff & 127;
    unsigned int pk[2];
#pragma unroll
    for (int i = 0; i < 2; i++)
      pk[i] = ((unsigned int)f2bf(dn * acc[2*i+1]) << 16) | f2bf(dn * acc[2*i]);
    int byte = (row * 256 + fe * 2) ^ ((row & 7) << 4);
    *(u32x2*)((char*)rha + byte) = *(u32x2*)pk;
  }
  __syncthreads();
  int ar = lane & 15;
  int koff = (lane >> 4) * 8;
  short8v afr[6];
  const unsigned short* xrow =
      Xa + (((size_t)s * NN + n0 + (ar >> 3)) * NB + (ar & 7)) * ND;
  afr[0] = *(const short8v*)(xrow + koff);
  afr[1] = *(const short8v*)(xrow + 32 + koff);
#pragma unroll
  for (int kb = 2; kb < 6; kb++) {
    int kk = (kb - 2) * 32 + koff;
    int byte = (ar * 256 + kk * 2) ^ ((ar & 7) << 4);
    afr[kb] = *(const short8v*)((char*)rha + byte);
  }
  f32x4 cacc = {0.f, 0.f, 0.f, 0.f};
  {
    const unsigned short* wcol = Wt + (size_t)(w * 16 + (lane & 15)) * 192;
#pragma unroll
    for (int kb = 0; kb < 6; kb++) {
      short8v bfr = *(const short8v*)(wcol + kb * 32 + koff);
      cacc = __builtin_amdgcn_mfma_f32_16x16x32_bf16(afr[kb], bfr, cacc, 0, 0, 0);
    }
  }
  // ---- epilogue: tanh, gate, LN
  int r0 = (lane >> 4) * 4;
  int col = w * 16 + (lane & 15);
  float u[4];
  float bcc = bc[col];
#pragma unroll
  for (int qq = 0; qq < 4; qq++) {
    int r = r0 + qq;
    size_t gidx = (((size_t)(n0 + (r >> 3))) * NB + (r & 7)) * NH + col;
    float gc = cacc[qq] + bcc;
    float ea = __expf(-2.f * fabsf(gc));
    float th = (1.f - ea) / (1.f + ea);
    float cand = copysignf(th, gc);
    float zv = (float)zH[gidx];
    float uu = (1.f - zv) * bf2f(hB[gidx]) + zv * cand;
    u[qq] = uu;
  }
#pragma unroll
  for (int qq = 0; qq < 4; qq++) {
    float s1 = u[qq], s2 = u[qq] * u[qq];
#pragma unroll
    for (int o = 1; o <= 8; o <<= 1) {
      s1 += __shfl_xor(s1, o, 64);
      s2 += __shfl_xor(s2, o, 64);
    }
    if ((lane & 15) == 0) {
      lsum[w][r0 + qq] = s1; lsq[w][r0 + qq] = s2;
    }
  }
  __syncthreads();
  float g = gamma[col], bt = beta[col];
#pragma unroll
  for (int qq = 0; qq < 4; qq++) {
    int r = r0 + qq;
    float tot = lsum[0][r] + lsum[1][r] + lsum[2][r] + lsum[3][r]
              + lsum[4][r] + lsum[5][r] + lsum[6][r] + lsum[7][r];
    float totq = lsq[0][r] + lsq[1][r] + lsq[2][r] + lsq[3][r]
               + lsq[4][r] + lsq[5][r] + lsq[6][r] + lsq[7][r];
    float mu = tot * (1.f / NH);
    float var = totq * (1.f / NH) - mu * mu;
    float inv = rsqrtf(var + LN_EPS);
    float hv = (u[qq] - mu) * inv * g + bt;
    size_t gidx = (((size_t)(n0 + (r >> 3))) * NB + (r & 7)) * NH + col;
    nts_us(f2bf(hv), hB + gidx);
  }
}

// ---------------- pool: out[b][f] = mean_n h[n][b][f] ----------------------

__global__ __launch_bounds__(128)
void k_pool(const unsigned short* __restrict__ hB, float* __restrict__ out) {
  int b = blockIdx.x & 7;
  int c = blockIdx.x >> 3;   // 16 chunks of 128 nodes
  int f = threadIdx.x;
  float acc = 0.f;
  for (int n = c * 128; n < c * 128 + 128; n++)
    acc += bf2f(hB[((size_t)n * NB + b) * NH + f]);
  atomicAdd(&out[b * NH + f], acc * (1.f / NN));
}

// ---------------- host ----------------------------------------------------

extern "C" void kernel_launch(void* const* d_in, const int* in_sizes, int n_in,
                              void* d_out, int out_size, void* d_ws, size_t ws_size,
                              hipStream_t stream) {
  const float* x     = (const float*)d_in[0];
  const int*   ei    = (const int*)d_in[1];
  const float* Wz    = (const float*)d_in[3];
  const float* bz    = (const float*)d_in[4];
  const float* Wr    = (const float*)d_in[5];
  const float* br    = (const float*)d_in[6];
  const float* Wc    = (const float*)d_in[7];
  const float* bc    = (const float*)d_in[8];
  const float* gamma = (const float*)d_in[9];
  const float* beta  = (const float*)d_in[10];
  float* out = (float*)d_out;

  char* ws = (char*)d_ws;
  size_t off = 0;
  auto alloc = [&](size_t bytes) {
    void* p = ws + off;
    off = (off + bytes + 255) & ~(size_t)255;
    return p;
  };
  unsigned short* hB   = (unsigned short*)alloc((size_t)NT * NH * 2);
  unsigned short* rhB  = (unsigned short*)alloc((size_t)NT * NH * 2);
  _Float16*       zH   = (_Float16*)alloc((size_t)NT * NH * 2);
  unsigned short* xT   = (unsigned short*)alloc((size_t)NS * NN * NB * ND * 2);
  unsigned short* Xa   = (unsigned short*)alloc((size_t)NS * NN * NB * ND * 2);
  unsigned short* Wt_zr = (unsigned short*)alloc((size_t)256 * 192 * 2);
  unsigned short* Wt_c  = (unsigned short*)alloc((size_t)128 * 192 * 2);
  float* dinv = (float*)alloc(NN * 4);
  int* deg       = (int*)alloc(NN * 4);
  int* row_start = (int*)alloc((NN + 1) * 4);
  int* cursor    = (int*)alloc(NN * 4);
  int* csr_src   = (int*)alloc(NE * 4);

  const int* e_src = ei;
  const int* e_dst = ei + NE;

  hipMemsetAsync(hB, 0, (size_t)NT * NH * 2, stream);
  hipMemsetAsync(deg, 0, NN * 4, stream);
  hipMemsetAsync(cursor, 0, NN * 4, stream);
  hipMemsetAsync(d_out, 0, (size_t)NB * NH * 4, stream);

  k_count<<<NE / 256, 256, 0, stream>>>(e_dst, deg);
  k_scan<<<1, 256, 0, stream>>>(deg, row_start, dinv);
  k_scatter<<<NE / 256, 256, 0, stream>>>(e_src, e_dst, row_start, cursor, csr_src);
  k_wcvt<<<256, 192, 0, stream>>>(Wz, Wr, Wc, Wt_zr, Wt_c);
  k_xT<<<16384, 256, 0, stream>>>(x, xT);
  k_aggX2<<<16384, 256, 0, stream>>>(xT, row_start, csr_src, dinv, Xa);

  for (int s = 0; s < NS; s++) {
    k_zrF<<<NN / 2, 512, 0, stream>>>(Xa, hB, Wt_zr, row_start, csr_src, dinv,
                                      bz, br, zH, rhB, s);
    k_cF<<<NN / 2, 512, 0, stream>>>(Xa, rhB, zH, Wt_c, row_start, csr_src, dinv,
                                     bc, gamma, beta, hB, s);
  }
  k_pool<<<128, 128, 0, stream>>>(hB, out);
}

// Round 10
// 1451.415 us; speedup vs baseline: 1.3696x; 1.3696x over previous
//
#include <hip/hip_runtime.h>
#include <math.h>

#define NB 8
#define NS 32
#define NN 2048
#define ND 64
#define NH 128
#define NE 32768
#define NT (NB*NN)
#define LN_EPS 1e-5f

typedef __attribute__((ext_vector_type(8))) short short8v;
typedef __attribute__((ext_vector_type(4))) float f32x4;
typedef __attribute__((ext_vector_type(4))) unsigned int u32x4;
typedef __attribute__((ext_vector_type(2))) unsigned int u32x2;

static __device__ inline unsigned short f2bf(float f) {
  union { float f; unsigned int u; } v; v.f = f;
  unsigned int r = v.u + 0x7fffu + ((v.u >> 16) & 1u);
  return (unsigned short)(r >> 16);
}
static __device__ inline float bf2f(unsigned short s) {
  union { unsigned int u; float f; } v; v.u = ((unsigned int)s) << 16;
  return v.f;
}

// 16B = 8 bf16 -> 8 fp32
static __device__ inline void bf8_to_f(const unsigned short* __restrict__ p, float* f) {
  u32x4 v = *(const u32x4*)p;
#pragma unroll
  for (int i = 0; i < 4; i++) {
    union { unsigned int u; float x; } lo, hi;
    lo.u = v[i] << 16; hi.u = v[i] & 0xFFFF0000u;
    f[2*i] = lo.x; f[2*i+1] = hi.x;
  }
}

// ---------------- CSR build (topology is time-invariant) ----------------

__global__ void k_count(const int* __restrict__ dst, int* __restrict__ deg) {
  int e = blockIdx.x * blockDim.x + threadIdx.x;
  if (e < NE) atomicAdd(&deg[dst[e]], 1);
}

__global__ void k_scan(const int* __restrict__ deg, int* __restrict__ row_start,
                       float* __restrict__ dinv) {
  if (threadIdx.x == 0) {
    int acc = 0;
    for (int n = 0; n < NN; n++) { row_start[n] = acc; acc += deg[n]; }
    row_start[NN] = acc;
  }
  for (int n = threadIdx.x; n < NN; n += blockDim.x) {
    dinv[n] = rsqrtf((float)(deg[n] + 1));
  }
}

__global__ void k_scatter(const int* __restrict__ src, const int* __restrict__ dst,
                          const int* __restrict__ row_start, int* __restrict__ cursor,
                          int* __restrict__ csr_src) {
  int e = blockIdx.x * blockDim.x + threadIdx.x;
  if (e < NE) {
    int d = dst[e];
    int pos = atomicAdd(&cursor[d], 1);
    csr_src[row_start[d] + pos] = src[e];
  }
}

// ---------------- weight transpose + bf16 convert (once) ----------------

__global__ void k_wcvt(const float* __restrict__ Wz, const float* __restrict__ Wr,
                       const float* __restrict__ Wc,
                       unsigned short* __restrict__ Wt_zr, unsigned short* __restrict__ Wt_c) {
  int col = blockIdx.x;   // 0..255
  int k = threadIdx.x;    // 0..191
  float v = (col < 128) ? Wz[k * 128 + col] : Wr[k * 128 + (col - 128)];
  Wt_zr[(size_t)col * 192 + k] = f2bf(v);
  if (col < 128) Wt_c[(size_t)col * 192 + k] = f2bf(Wc[k * 128 + col]);
}

// ---------------- transpose x -> xT[s][n][b][64] bf16 ----------------

__global__ __launch_bounds__(256)
void k_xT(const float* __restrict__ x, unsigned short* __restrict__ xT) {
  int blk = blockIdx.x;          // 16384 blocks: (s, group of 4 n)
  int s = blk >> 9;
  int n0 = (blk & 511) * 4;
  int t = threadIdx.x;
  int b = t >> 5;
  int d2 = (t & 31) * 2;
#pragma unroll
  for (int i = 0; i < 4; i++) {
    int n = n0 + i;
    const float2 v = *(const float2*)(x + (((size_t)b * NS + s) * NN + n) * ND + d2);
    unsigned int p = ((unsigned int)f2bf(v.y) << 16) | f2bf(v.x);
    *(unsigned int*)(xT + (((size_t)s * NN + n) * NB + b) * ND + d2) = p;
  }
}

// ---------------- Xa[s][n][b][64] = A_hat @ x (all steps) -----------------
// scalar-uniform gather: n is wave-uniform (readfirstlane) so csr_src[k] and
// dinv[sn] compile to s_load (SMEM), removing shfl-broadcast from the
// per-neighbor critical path.

__global__ __launch_bounds__(256)
void k_aggX2(const unsigned short* __restrict__ xT, const int* __restrict__ row_start,
             const int* __restrict__ csr_src, const float* __restrict__ dinv,
             unsigned short* __restrict__ Xa) {
  int bid = blockIdx.x;                     // 16384
  int bs = (bid & 7) * 2048 + (bid >> 3);   // XCD chunking: 4 s-slabs per XCD
  int rid = bs * 4 + (threadIdx.x >> 6);    // (s,n) id, 0..65535
  int lane = threadIdx.x & 63;
  int s = rid >> 11;
  int n = __builtin_amdgcn_readfirstlane(rid & 2047);
  const unsigned short* xs = xT + (size_t)s * (NN * NB * ND);
  float dn = dinv[n];
  float acc[8], val[8];
  bf8_to_f(xs + (size_t)n * 512 + lane * 8, val);
#pragma unroll
  for (int i = 0; i < 8; i++) acc[i] = dn * val[i];
  int k0 = __builtin_amdgcn_readfirstlane(row_start[n]);
  int k1 = __builtin_amdgcn_readfirstlane(row_start[n + 1]);
#pragma unroll 4
  for (int k = k0; k < k1; k++) {
    int sn = csr_src[k];          // uniform -> s_load
    float ww = dinv[sn];          // uniform -> s_load
    bf8_to_f(xs + (size_t)sn * 512 + lane * 8, val);
#pragma unroll
    for (int i = 0; i < 8; i++) acc[i] = fmaf(ww, val[i], acc[i]);
  }
  unsigned int pk[4];
#pragma unroll
  for (int i = 0; i < 4; i++)
    pk[i] = ((unsigned int)f2bf(dn * acc[2*i+1]) << 16) | f2bf(dn * acc[2*i]);
  *(u32x4*)(Xa + (size_t)rid * 512 + lane * 8) = *(u32x4*)pk;
}

// ---------------- phase A: agg(hB) + [Xa|ha]@[Wz|Wr] + gates ----------------
// 256 thr = 4 waves, 2 nodes/block (round-4 geometry, best measured).
// Gather: wave w -> node j=w>>1, half=w&1 (16B/lane). GEMM rows 16
// (r: n=n0+(r>>3), b=r&7); wave w -> col-tiles 4w..4w+3 of [Wz|Wr].

__global__ __launch_bounds__(256)
void k_zrF(const unsigned short* __restrict__ Xa, const unsigned short* __restrict__ hB,
           const unsigned short* __restrict__ Wt,
           const int* __restrict__ row_start, const int* __restrict__ csr_src,
           const float* __restrict__ dinv,
           const float* __restrict__ bz, const float* __restrict__ br,
           _Float16* __restrict__ zH, unsigned short* __restrict__ rhB, int s) {
  __shared__ unsigned short ha[16 * 128];
  int tid = threadIdx.x;
  int lane = tid & 63;
  int w = tid >> 6;
  int n0 = blockIdx.x * 2;
  int j = w >> 1, half = w & 1;
  int n = __builtin_amdgcn_readfirstlane(n0 + j);
  float dn = dinv[n];
  float acc[8], val[8];
  int foff = half * 512 + lane * 8;         // element in [0,1024) of node row
  bf8_to_f(hB + (size_t)n * (NB * NH) + foff, val);
#pragma unroll
  for (int i = 0; i < 8; i++) acc[i] = dn * val[i];
  int k0 = __builtin_amdgcn_readfirstlane(row_start[n]);
  int k1 = __builtin_amdgcn_readfirstlane(row_start[n + 1]);
#pragma unroll 4
  for (int k = k0; k < k1; k++) {
    int sn = csr_src[k];
    float ww = dinv[sn];
    bf8_to_f(hB + (size_t)sn * (NB * NH) + foff, val);
#pragma unroll
    for (int i = 0; i < 8; i++) acc[i] = fmaf(ww, val[i], acc[i]);
  }
  {  // LDS [16][128] bf16, XOR-swizzled; row = j*8 + b
    int row = j * 8 + (foff >> 7);
    int fe = foff & 127;
    unsigned int pk[4];
#pragma unroll
    for (int i = 0; i < 4; i++)
      pk[i] = ((unsigned int)f2bf(dn * acc[2*i+1]) << 16) | f2bf(dn * acc[2*i]);
    int byte = (row * 256 + fe * 2) ^ ((row & 7) << 4);
    *(u32x4*)((char*)ha + byte) = *(u32x4*)pk;
  }
  __syncthreads();
  // ---- GEMM 16 rows x 256 cols
  int ar = lane & 15;
  int koff = (lane >> 4) * 8;
  short8v afr[6];
  const unsigned short* xrow =
      Xa + (((size_t)s * NN + n0 + (ar >> 3)) * NB + (ar & 7)) * ND;
  afr[0] = *(const short8v*)(xrow + koff);
  afr[1] = *(const short8v*)(xrow + 32 + koff);
#pragma unroll
  for (int kb = 2; kb < 6; kb++) {
    int kk = (kb - 2) * 32 + koff;
    int byte = (ar * 256 + kk * 2) ^ ((ar & 7) << 4);
    afr[kb] = *(const short8v*)((char*)ha + byte);
  }
  f32x4 cacc[4];
#pragma unroll
  for (int ct = 0; ct < 4; ct++) cacc[ct] = (f32x4){0.f, 0.f, 0.f, 0.f};
#pragma unroll
  for (int ct = 0; ct < 4; ct++) {
    const unsigned short* wcol = Wt + (size_t)((w * 4 + ct) * 16 + (lane & 15)) * 192;
#pragma unroll
    for (int kb = 0; kb < 6; kb++) {
      short8v bfr = *(const short8v*)(wcol + kb * 32 + koff);
      cacc[ct] = __builtin_amdgcn_mfma_f32_16x16x32_bf16(afr[kb], bfr, cacc[ct], 0, 0, 0);
    }
  }
  // ---- epilogue: cols 0-127 -> z (fp16); cols 128-255 -> rhB = sigmoid(r)*h
  int r0 = (lane >> 4) * 4;
#pragma unroll
  for (int ct = 0; ct < 4; ct++) {
    int col = (w * 4 + ct) * 16 + (lane & 15);
    int isz = (col < 128);
    int f = isz ? col : col - 128;
    float bias = isz ? bz[f] : br[f];
#pragma unroll
    for (int qq = 0; qq < 4; qq++) {
      int r = r0 + qq;
      size_t gidx = (((size_t)(n0 + (r >> 3))) * NB + (r & 7)) * NH + f;
      float g = cacc[ct][qq] + bias;
      float sg = 1.f / (1.f + __expf(-g));
      if (isz) zH[gidx] = (_Float16)sg;
      else rhB[gidx] = f2bf(sg * bf2f(hB[gidx]));
    }
  }
}

// ---------------- phase B: agg(rhB) + @Wc + tanh + gate + LN ----------------
// 256 thr; wave w -> col-tiles 2w,2w+1. LN across 4 waves via LDS.

__global__ __launch_bounds__(256)
void k_cF(const unsigned short* __restrict__ Xa, const unsigned short* __restrict__ rhB,
          const _Float16* __restrict__ zH, const unsigned short* __restrict__ Wt,
          const int* __restrict__ row_start, const int* __restrict__ csr_src,
          const float* __restrict__ dinv, const float* __restrict__ bc,
          const float* __restrict__ gamma, const float* __restrict__ beta,
          unsigned short* __restrict__ hB, int s) {
  __shared__ unsigned short rha[16 * 128];
  __shared__ float lsum[4][16], lsq[4][16];
  int tid = threadIdx.x;
  int lane = tid & 63;
  int w = tid >> 6;
  int n0 = blockIdx.x * 2;
  int j = w >> 1, half = w & 1;
  int n = __builtin_amdgcn_readfirstlane(n0 + j);
  float dn = dinv[n];
  float acc[8], val[8];
  int foff = half * 512 + lane * 8;
  bf8_to_f(rhB + (size_t)n * (NB * NH) + foff, val);
#pragma unroll
  for (int i = 0; i < 8; i++) acc[i] = dn * val[i];
  int k0 = __builtin_amdgcn_readfirstlane(row_start[n]);
  int k1 = __builtin_amdgcn_readfirstlane(row_start[n + 1]);
#pragma unroll 4
  for (int k = k0; k < k1; k++) {
    int sn = csr_src[k];
    float ww = dinv[sn];
    bf8_to_f(rhB + (size_t)sn * (NB * NH) + foff, val);
#pragma unroll
    for (int i = 0; i < 8; i++) acc[i] = fmaf(ww, val[i], acc[i]);
  }
  {
    int row = j * 8 + (foff >> 7);
    int fe = foff & 127;
    unsigned int pk[4];
#pragma unroll
    for (int i = 0; i < 4; i++)
      pk[i] = ((unsigned int)f2bf(dn * acc[2*i+1]) << 16) | f2bf(dn * acc[2*i]);
    int byte = (row * 256 + fe * 2) ^ ((row & 7) << 4);
    *(u32x4*)((char*)rha + byte) = *(u32x4*)pk;
  }
  __syncthreads();
  int ar = lane & 15;
  int koff = (lane >> 4) * 8;
  short8v afr[6];
  const unsigned short* xrow =
      Xa + (((size_t)s * NN + n0 + (ar >> 3)) * NB + (ar & 7)) * ND;
  afr[0] = *(const short8v*)(xrow + koff);
  afr[1] = *(const short8v*)(xrow + 32 + koff);
#pragma unroll
  for (int kb = 2; kb < 6; kb++) {
    int kk = (kb - 2) * 32 + koff;
    int byte = (ar * 256 + kk * 2) ^ ((ar & 7) << 4);
    afr[kb] = *(const short8v*)((char*)rha + byte);
  }
  f32x4 cacc[2];
  cacc[0] = (f32x4){0.f, 0.f, 0.f, 0.f};
  cacc[1] = (f32x4){0.f, 0.f, 0.f, 0.f};
#pragma unroll
  for (int ct = 0; ct < 2; ct++) {
    const unsigned short* wcol = Wt + (size_t)((w * 2 + ct) * 16 + (lane & 15)) * 192;
#pragma unroll
    for (int kb = 0; kb < 6; kb++) {
      short8v bfr = *(const short8v*)(wcol + kb * 32 + koff);
      cacc[ct] = __builtin_amdgcn_mfma_f32_16x16x32_bf16(afr[kb], bfr, cacc[ct], 0, 0, 0);
    }
  }
  // ---- epilogue: tanh, gate, LN
  int r0 = (lane >> 4) * 4;
  float u[2][4];
  float psum[4] = {0.f, 0.f, 0.f, 0.f};
  float psq[4] = {0.f, 0.f, 0.f, 0.f};
#pragma unroll
  for (int ct = 0; ct < 2; ct++) {
    int col = (w * 2 + ct) * 16 + (lane & 15);
    float bcc = bc[col];
#pragma unroll
    for (int qq = 0; qq < 4; qq++) {
      int r = r0 + qq;
      size_t gidx = (((size_t)(n0 + (r >> 3))) * NB + (r & 7)) * NH + col;
      float gc = cacc[ct][qq] + bcc;
      float ea = __expf(-2.f * fabsf(gc));
      float th = (1.f - ea) / (1.f + ea);
      float cand = copysignf(th, gc);
      float zv = (float)zH[gidx];
      float uu = (1.f - zv) * bf2f(hB[gidx]) + zv * cand;
      u[ct][qq] = uu;
      psum[qq] += uu; psq[qq] += uu * uu;
    }
  }
#pragma unroll
  for (int qq = 0; qq < 4; qq++) {
    float s1 = psum[qq], s2 = psq[qq];
#pragma unroll
    for (int o = 1; o <= 8; o <<= 1) {
      s1 += __shfl_xor(s1, o, 64);
      s2 += __shfl_xor(s2, o, 64);
    }
    if ((lane & 15) == 0) {
      lsum[w][r0 + qq] = s1; lsq[w][r0 + qq] = s2;
    }
  }
  __syncthreads();
#pragma unroll
  for (int ct = 0; ct < 2; ct++) {
    int col = (w * 2 + ct) * 16 + (lane & 15);
    float g = gamma[col], bt = beta[col];
#pragma unroll
    for (int qq = 0; qq < 4; qq++) {
      int r = r0 + qq;
      float tot = lsum[0][r] + lsum[1][r] + lsum[2][r] + lsum[3][r];
      float totq = lsq[0][r] + lsq[1][r] + lsq[2][r] + lsq[3][r];
      float mu = tot * (1.f / NH);
      float var = totq * (1.f / NH) - mu * mu;
      float inv = rsqrtf(var + LN_EPS);
      float hv = (u[ct][qq] - mu) * inv * g + bt;
      size_t gidx = (((size_t)(n0 + (r >> 3))) * NB + (r & 7)) * NH + col;
      hB[gidx] = f2bf(hv);
    }
  }
}

// ---------------- pool: out[b][f] = mean_n h[n][b][f] ----------------------

__global__ __launch_bounds__(128)
void k_pool(const unsigned short* __restrict__ hB, float* __restrict__ out) {
  int b = blockIdx.x & 7;
  int c = blockIdx.x >> 3;   // 16 chunks of 128 nodes
  int f = threadIdx.x;
  float acc = 0.f;
  for (int n = c * 128; n < c * 128 + 128; n++)
    acc += bf2f(hB[((size_t)n * NB + b) * NH + f]);
  atomicAdd(&out[b * NH + f], acc * (1.f / NN));
}

// ---------------- host ----------------------------------------------------

extern "C" void kernel_launch(void* const* d_in, const int* in_sizes, int n_in,
                              void* d_out, int out_size, void* d_ws, size_t ws_size,
                              hipStream_t stream) {
  const float* x     = (const float*)d_in[0];
  const int*   ei    = (const int*)d_in[1];
  const float* Wz    = (const float*)d_in[3];
  const float* bz    = (const float*)d_in[4];
  const float* Wr    = (const float*)d_in[5];
  const float* br    = (const float*)d_in[6];
  const float* Wc    = (const float*)d_in[7];
  const float* bc    = (const float*)d_in[8];
  const float* gamma = (const float*)d_in[9];
  const float* beta  = (const float*)d_in[10];
  float* out = (float*)d_out;

  char* ws = (char*)d_ws;
  size_t off = 0;
  auto alloc = [&](size_t bytes) {
    void* p = ws + off;
    off = (off + bytes + 255) & ~(size_t)255;
    return p;
  };
  unsigned short* hB   = (unsigned short*)alloc((size_t)NT * NH * 2);
  unsigned short* rhB  = (unsigned short*)alloc((size_t)NT * NH * 2);
  _Float16*       zH   = (_Float16*)alloc((size_t)NT * NH * 2);
  unsigned short* xT   = (unsigned short*)alloc((size_t)NS * NN * NB * ND * 2);
  unsigned short* Xa   = (unsigned short*)alloc((size_t)NS * NN * NB * ND * 2);
  unsigned short* Wt_zr = (unsigned short*)alloc((size_t)256 * 192 * 2);
  unsigned short* Wt_c  = (unsigned short*)alloc((size_t)128 * 192 * 2);
  float* dinv = (float*)alloc(NN * 4);
  int* deg       = (int*)alloc(NN * 4);
  int* row_start = (int*)alloc((NN + 1) * 4);
  int* cursor    = (int*)alloc(NN * 4);
  int* csr_src   = (int*)alloc(NE * 4);

  const int* e_src = ei;
  const int* e_dst = ei + NE;

  hipMemsetAsync(hB, 0, (size_t)NT * NH * 2, stream);
  hipMemsetAsync(deg, 0, NN * 4, stream);
  hipMemsetAsync(cursor, 0, NN * 4, stream);
  hipMemsetAsync(d_out, 0, (size_t)NB * NH * 4, stream);

  k_count<<<NE / 256, 256, 0, stream>>>(e_dst, deg);
  k_scan<<<1, 256, 0, stream>>>(deg, row_start, dinv);
  k_scatter<<<NE / 256, 256, 0, stream>>>(e_src, e_dst, row_start, cursor, csr_src);
  k_wcvt<<<256, 192, 0, stream>>>(Wz, Wr, Wc, Wt_zr, Wt_c);
  k_xT<<<16384, 256, 0, stream>>>(x, xT);
  k_aggX2<<<16384, 256, 0, stream>>>(xT, row_start, csr_src, dinv, Xa);

  for (int s = 0; s < NS; s++) {
    k_zrF<<<NN / 2, 256, 0, stream>>>(Xa, hB, Wt_zr, row_start, csr_src, dinv,
                                      bz, br, zH, rhB, s);
    k_cF<<<NN / 2, 256, 0, stream>>>(Xa, rhB, zH, Wt_c, row_start, csr_src, dinv,
                                     bc, gamma, beta, hB, s);
  }
  k_pool<<<128, 128, 0, stream>>>(hB, out);
}